// Round 1
// baseline (426.219 us; speedup 1.0000x reference)
//
#include <hip/hip_runtime.h>
#include <stdint.h>

// HealthAttention: out = (softmax(rope(XWq^T) rope(XWk^T)^T / sqrt(128)) XWv^T) Wo^T
// B=2 S=2048 D=2048 H=16 DH=128.  medical_bias is per-head constant over the
// softmax axis -> softmax-invariant -> dropped.
// Pipeline: f32->bf16 converts | rope table | QKV GEMM (bf16 MFMA, V written
// transposed per-head) | RoPE (Q scaled by 1/sqrt(128)) | flash attention |
// output GEMM.

#define B_ 2
#define S_ 2048
#define D_ 2048
#define H_ 16

typedef float f32x4 __attribute__((ext_vector_type(4)));
typedef short s16x8 __attribute__((ext_vector_type(8)));

__device__ __forceinline__ unsigned short f2bf(float f) {
  union { float f; uint32_t u; } c; c.f = f;
  return (unsigned short)((c.u + 0x7fffu + ((c.u >> 16) & 1u)) >> 16);
}

__device__ __forceinline__ void gld_lds16(const void* g, void* l) {
  __builtin_amdgcn_global_load_lds(
      (const __attribute__((address_space(1))) uint32_t*)g,
      (__attribute__((address_space(3))) uint32_t*)l, 16, 0, 0);
}

// ---------------- fp32 -> bf16 convert ----------------
__global__ __launch_bounds__(256) void k_f2bf(const float* __restrict__ in,
                                              unsigned short* __restrict__ out,
                                              int n4) {
  int i = blockIdx.x * 256 + threadIdx.x;
  int stride = gridDim.x * 256;
  for (; i < n4; i += stride) {
    f32x4 v = ((const f32x4*)in)[i];
    ushort4 o;
    o.x = f2bf(v.x); o.y = f2bf(v.y); o.z = f2bf(v.z); o.w = f2bf(v.w);
    ((ushort4*)out)[i] = o;
  }
}

// ---------------- rope tables: cos/sin [S][64] ----------------
__global__ __launch_bounds__(256) void k_tab(float* __restrict__ tc,
                                             float* __restrict__ ts) {
  int t = blockIdx.x * 256 + threadIdx.x;  // 0..131071
  int s = t >> 6, j = t & 63;
  // inv_freq = 10000^(-j/64)
  float inv = expf(-(float)j * (1.0f / 64.0f) * 9.210340371976184f);
  float ang = (float)s * inv;
  float sv, cv;
  sincosf(ang, &sv, &cv);
  tc[t] = cv;
  ts[t] = sv;
}

// ---------------- GEMM: C[M,N] = A[M,K] @ W[N,K]^T  (bf16 in, fp32 acc) -----
// 128x128 tile, BK=64, 4 waves (2x2), 16x16x32 MFMA.
// z=0 -> fp32 to C0; z=1 -> fp32 to C1; z=2 -> bf16 transposed per-head to VT.
__global__ __launch_bounds__(256, 2) void k_gemm(
    const unsigned short* __restrict__ A,
    const unsigned short* __restrict__ W0,
    const unsigned short* __restrict__ W1,
    const unsigned short* __restrict__ W2,
    float* __restrict__ C0,
    float* __restrict__ C1,
    unsigned short* __restrict__ VT) {
  __shared__ unsigned short Al[128 * 64];
  __shared__ unsigned short Bl[128 * 64];

  const int z = blockIdx.z;
  const unsigned short* __restrict__ Wp = (z == 0) ? W0 : (z == 1) ? W1 : W2;

  const int tid = threadIdx.x;
  const int w = tid >> 6;
  const int l = tid & 63;
  const int wr = w >> 1, wc = w & 1;
  const int row0 = (int)blockIdx.y * 128;
  const int col0 = (int)blockIdx.x * 128;

  const int srow = l >> 3;        // staging: 8 rows x 128B per wave-issue
  const int scol = (l & 7) << 3;  // bf16 elems
  const int c16 = l & 15, g = l >> 4;

  f32x4 acc[4][4];
#pragma unroll
  for (int m = 0; m < 4; ++m)
#pragma unroll
    for (int n = 0; n < 4; ++n)
      acc[m][n] = f32x4{0.f, 0.f, 0.f, 0.f};

  for (int k0 = 0; k0 < 2048; k0 += 64) {
#pragma unroll
    for (int i = 0; i < 4; ++i) {
      const int jj = (w << 2) + i;  // 0..15, wave-uniform
      gld_lds16(&A[(size_t)(row0 + (jj << 3) + srow) * 2048 + k0 + scol],
                &Al[jj * 512]);
      gld_lds16(&Wp[(size_t)(col0 + (jj << 3) + srow) * 2048 + k0 + scol],
                &Bl[jj * 512]);
    }
    __syncthreads();
#pragma unroll
    for (int kk = 0; kk < 2; ++kk) {
      const int cc = kk * 32 + g * 8;
      s16x8 a[4], b[4];
#pragma unroll
      for (int m = 0; m < 4; ++m)
        a[m] = *(const s16x8*)&Al[(wr * 64 + m * 16 + c16) * 64 + cc];
#pragma unroll
      for (int n = 0; n < 4; ++n)
        b[n] = *(const s16x8*)&Bl[(wc * 64 + n * 16 + c16) * 64 + cc];
#pragma unroll
      for (int m = 0; m < 4; ++m)
#pragma unroll
        for (int n = 0; n < 4; ++n)
          acc[m][n] =
              __builtin_amdgcn_mfma_f32_16x16x32_bf16(a[m], b[n], acc[m][n], 0, 0, 0);
    }
    __syncthreads();
  }

  if (z < 2) {
    float* __restrict__ C = (z == 0) ? C0 : C1;
#pragma unroll
    for (int m = 0; m < 4; ++m) {
      const int gr = row0 + wr * 64 + m * 16 + g * 4;
#pragma unroll
      for (int n = 0; n < 4; ++n) {
        const int gc = col0 + wc * 64 + n * 16 + c16;
#pragma unroll
        for (int r = 0; r < 4; ++r)
          C[(size_t)(gr + r) * 2048 + gc] = acc[m][n][r];
      }
    }
  } else {
    // V: write bf16 transposed per-head: VT[((b*16+h)*128+dh)*2048 + s]
#pragma unroll
    for (int m = 0; m < 4; ++m) {
      const int gr = row0 + wr * 64 + m * 16 + g * 4;  // 4 consecutive s
      const int b_ = gr >> 11, s_ = gr & 2047;
#pragma unroll
      for (int n = 0; n < 4; ++n) {
        const int gc = col0 + wc * 64 + n * 16 + c16;  // h*128+dh
        ushort4 o;
        o.x = f2bf(acc[m][n][0]);
        o.y = f2bf(acc[m][n][1]);
        o.z = f2bf(acc[m][n][2]);
        o.w = f2bf(acc[m][n][3]);
        *(ushort4*)&VT[((size_t)(b_ * 2048 + gc)) * 2048 + s_] = o;
      }
    }
  }
}

// ---------------- RoPE: fp32 in -> bf16 out; z=0 Q(scaled), z=1 K ----------
__global__ __launch_bounds__(256) void k_rope(const float* __restrict__ Qf,
                                              const float* __restrict__ Kf,
                                              unsigned short* __restrict__ Qb,
                                              unsigned short* __restrict__ Kb,
                                              const float* __restrict__ tc,
                                              const float* __restrict__ ts) {
  const float* __restrict__ in = blockIdx.z ? Kf : Qf;
  unsigned short* __restrict__ out = blockIdx.z ? Kb : Qb;
  const float scale = blockIdx.z ? 1.0f : 0.08838834764831845f;  // 1/sqrt(128)
  int u = blockIdx.x * 256 + threadIdx.x;
  const int total = B_ * S_ * H_ * 16;  // 1048576 quad-units
  for (; u < total; u += gridDim.x * 256) {
    int bs = u >> 8;
    int rem = u & 255;
    int h = rem >> 4, j4 = rem & 15;
    int s = bs & 2047;
    size_t base = (size_t)bs * 2048 + h * 128 + j4 * 4;
    f32x4 x1 = *(const f32x4*)&in[base];
    f32x4 x2 = *(const f32x4*)&in[base + 64];
    f32x4 c = *(const f32x4*)&tc[s * 64 + j4 * 4];
    f32x4 sn = *(const f32x4*)&ts[s * 64 + j4 * 4];
    f32x4 o1 = (x1 * c - x2 * sn) * scale;
    f32x4 o2 = (x2 * c + x1 * sn) * scale;
    ushort4 oa, ob;
    oa.x = f2bf(o1.x); oa.y = f2bf(o1.y); oa.z = f2bf(o1.z); oa.w = f2bf(o1.w);
    ob.x = f2bf(o2.x); ob.y = f2bf(o2.y); ob.z = f2bf(o2.z); ob.w = f2bf(o2.w);
    *(ushort4*)&out[base] = oa;
    *(ushort4*)&out[base + 64] = ob;
  }
}

// ---------------- flash attention ----------------
// grid (16, 32): x = q-block (128 rows), y = b*16+h. 4 waves x 32 q-rows.
__global__ __launch_bounds__(256, 1) void k_attn(
    const unsigned short* __restrict__ Qb,
    const unsigned short* __restrict__ Kb,
    const unsigned short* __restrict__ Vt,
    unsigned short* __restrict__ Ob) {
  __shared__ unsigned short Kl[64 * 128];   // [key][d]
  __shared__ unsigned short Vl[128 * 64];   // [d][key]  (from Vt)
  __shared__ unsigned short Pl[4][32 * 64]; // per-wave P

  const int tid = threadIdx.x, w = tid >> 6, l = tid & 63;
  const int bh = blockIdx.y;
  const int b = bh >> 4, h = bh & 15;
  const int q0 = (int)blockIdx.x * 128 + w * 32;
  const int g = l >> 4, c16 = l & 15;

  // Q fragments in registers (scores pre-scaled via Q)
  s16x8 qf[2][4];
#pragma unroll
  for (int qq = 0; qq < 2; ++qq)
#pragma unroll
    for (int kc = 0; kc < 4; ++kc)
      qf[qq][kc] = *(const s16x8*)&Qb[(size_t)(b * 2048 + q0 + qq * 16 + c16) * 2048 +
                                      h * 128 + kc * 32 + g * 8];

  f32x4 oacc[2][8];
  float mrow[2][4], lrow[2][4];
#pragma unroll
  for (int qq = 0; qq < 2; ++qq) {
#pragma unroll
    for (int df = 0; df < 8; ++df) oacc[qq][df] = f32x4{0.f, 0.f, 0.f, 0.f};
#pragma unroll
    for (int r = 0; r < 4; ++r) { mrow[qq][r] = -INFINITY; lrow[qq][r] = 0.f; }
  }

  const int srow8 = l >> 3, scol8 = (l & 7) << 3;    // V staging
  const int srow16 = l >> 4, scol16 = (l & 15) << 3; // K staging

  for (int t = 0; t < 2048; t += 64) {
#pragma unroll
    for (int i = 0; i < 4; ++i) {
      const int jj = (w << 2) + i;  // 0..15
      gld_lds16(&Kb[(size_t)(b * 2048 + t + jj * 4 + srow16) * 2048 + h * 128 + scol16],
                &Kl[jj * 4 * 128]);
      gld_lds16(&Vt[(size_t)(bh * 128 + jj * 8 + srow8) * 2048 + t + scol8],
                &Vl[jj * 8 * 64]);
    }
    __syncthreads();

    // S = Q K^T  (pre-scaled)
    f32x4 sacc[2][4];
#pragma unroll
    for (int qq = 0; qq < 2; ++qq)
#pragma unroll
      for (int n = 0; n < 4; ++n) sacc[qq][n] = f32x4{0.f, 0.f, 0.f, 0.f};
#pragma unroll
    for (int kc = 0; kc < 4; ++kc) {
      s16x8 kb[4];
#pragma unroll
      for (int n = 0; n < 4; ++n)
        kb[n] = *(const s16x8*)&Kl[(n * 16 + c16) * 128 + kc * 32 + g * 8];
#pragma unroll
      for (int qq = 0; qq < 2; ++qq)
#pragma unroll
        for (int n = 0; n < 4; ++n)
          sacc[qq][n] =
              __builtin_amdgcn_mfma_f32_16x16x32_bf16(qf[qq][kc], kb[n], sacc[qq][n], 0, 0, 0);
    }

    // online softmax (rows = qq*16 + g*4 + r, cols in lanes c16 x 4 frags)
#pragma unroll
    for (int qq = 0; qq < 2; ++qq) {
#pragma unroll
      for (int r = 0; r < 4; ++r) {
        float mx = fmaxf(fmaxf(sacc[qq][0][r], sacc[qq][1][r]),
                         fmaxf(sacc[qq][2][r], sacc[qq][3][r]));
        mx = fmaxf(mx, __shfl_xor(mx, 1));
        mx = fmaxf(mx, __shfl_xor(mx, 2));
        mx = fmaxf(mx, __shfl_xor(mx, 4));
        mx = fmaxf(mx, __shfl_xor(mx, 8));
        float mnew = fmaxf(mrow[qq][r], mx);
        float alpha = __expf(mrow[qq][r] - mnew);
        mrow[qq][r] = mnew;
        float rs = 0.f;
#pragma unroll
        for (int n = 0; n < 4; ++n) {
          float p = __expf(sacc[qq][n][r] - mnew);
          sacc[qq][n][r] = p;
          rs += p;
        }
        rs += __shfl_xor(rs, 1);
        rs += __shfl_xor(rs, 2);
        rs += __shfl_xor(rs, 4);
        rs += __shfl_xor(rs, 8);
        lrow[qq][r] = lrow[qq][r] * alpha + rs;
#pragma unroll
        for (int df = 0; df < 8; ++df) oacc[qq][df][r] *= alpha;
      }
      // P -> per-wave LDS (bf16)
#pragma unroll
      for (int n = 0; n < 4; ++n)
#pragma unroll
        for (int r = 0; r < 4; ++r)
          Pl[w][(qq * 16 + g * 4 + r) * 64 + n * 16 + c16] = f2bf(sacc[qq][n][r]);
    }

    // O += P V   (P: [q][k], V from Vl: [d][k])
#pragma unroll
    for (int kc2 = 0; kc2 < 2; ++kc2) {
      s16x8 pa[2];
#pragma unroll
      for (int qq = 0; qq < 2; ++qq)
        pa[qq] = *(const s16x8*)&Pl[w][(qq * 16 + c16) * 64 + kc2 * 32 + g * 8];
#pragma unroll
      for (int df = 0; df < 8; ++df) {
        s16x8 vb = *(const s16x8*)&Vl[(df * 16 + c16) * 64 + kc2 * 32 + g * 8];
#pragma unroll
        for (int qq = 0; qq < 2; ++qq)
          oacc[qq][df] =
              __builtin_amdgcn_mfma_f32_16x16x32_bf16(pa[qq], vb, oacc[qq][df], 0, 0, 0);
      }
    }
    __syncthreads();
  }

  // epilogue: divide by softmax denom, write bf16 [B,S,D]
#pragma unroll
  for (int qq = 0; qq < 2; ++qq)
#pragma unroll
    for (int r = 0; r < 4; ++r) {
      const float inv = 1.0f / lrow[qq][r];
      const int srow_ = q0 + qq * 16 + g * 4 + r;
#pragma unroll
      for (int df = 0; df < 8; ++df)
        Ob[(size_t)(b * 2048 + srow_) * 2048 + h * 128 + df * 16 + c16] =
            f2bf(oacc[qq][df][r] * inv);
    }
}

// ---------------- launch ----------------
extern "C" void kernel_launch(void* const* d_in, const int* in_sizes, int n_in,
                              void* d_out, int out_size, void* d_ws, size_t ws_size,
                              hipStream_t stream) {
  const float* hs = (const float*)d_in[0];
  const float* Wq = (const float*)d_in[1];
  const float* Wk = (const float*)d_in[2];
  const float* Wv = (const float*)d_in[3];
  const float* Wo = (const float*)d_in[4];
  // d_in[5] medical_bias: per-head constant over softmax axis -> no-op.
  float* out = (float*)d_out;
  char* ws = (char*)d_ws;

  // workspace layout (bytes)
  unsigned short* hb  = (unsigned short*)(ws + 0);          // 16.78 MB (reused as Ob)
  unsigned short* wqb = (unsigned short*)(ws + 16777216);   // 8.39 MB
  unsigned short* wkb = (unsigned short*)(ws + 25165824);
  unsigned short* wvb = (unsigned short*)(ws + 33554432);
  unsigned short* wob = (unsigned short*)(ws + 41943040);
  float*          Qf  = (float*)(ws + 50331648);            // 33.55 MB
  float*          Kf  = (float*)(ws + 83886080);
  unsigned short* Vt  = (unsigned short*)(ws + 117440512);  // 16.78 MB
  unsigned short* Qbb = (unsigned short*)(ws + 134217728);
  unsigned short* Kbb = (unsigned short*)(ws + 150994944);
  float*          tabc = (float*)(ws + 167772160);          // 512 KB
  float*          tabs = (float*)(ws + 168296448);
  unsigned short* Ob  = hb;  // hidden-bf16 region reused after QKV GEMM

  k_f2bf<<<1024, 256, 0, stream>>>(hs, hb, 2097152);
  k_f2bf<<<1024, 256, 0, stream>>>(Wq, wqb, 1048576);
  k_f2bf<<<1024, 256, 0, stream>>>(Wk, wkb, 1048576);
  k_f2bf<<<1024, 256, 0, stream>>>(Wv, wvb, 1048576);
  k_f2bf<<<1024, 256, 0, stream>>>(Wo, wob, 1048576);
  k_tab<<<512, 256, 0, stream>>>(tabc, tabs);

  k_gemm<<<dim3(16, 32, 3), 256, 0, stream>>>(hb, wqb, wkb, wvb, Qf, Kf, Vt);
  k_rope<<<dim3(1024, 1, 2), 256, 0, stream>>>(Qf, Kf, Qbb, Kbb, tabc, tabs);
  k_attn<<<dim3(16, 32), 256, 0, stream>>>(Qbb, Kbb, Vt, Ob);
  k_gemm<<<dim3(16, 32, 1), 256, 0, stream>>>(Ob, wob, nullptr, nullptr, out,
                                              nullptr, nullptr);
}